// Round 11
// baseline (239.522 us; speedup 1.0000x reference)
//
#include <hip/hip_runtime.h>
#include <hip/hip_bf16.h>
#include <math.h>

typedef __bf16 bf16;
typedef __bf16 v8bf __attribute__((ext_vector_type(8)));
typedef __bf16 v4bf __attribute__((ext_vector_type(4)));
typedef __bf16 v2bf __attribute__((ext_vector_type(2)));
typedef float f32x4 __attribute__((ext_vector_type(4)));
typedef float f32x16 __attribute__((ext_vector_type(16)));

#define L_SEQ 4096
#define DMODEL 1024
#define NHEADS 16
#define DH 64
#define NEG_BIG (-1e30f)
#define LN1E4_64 0.14391156f   // ln(10000)/64
#define SCL2 0.18033688f       // 0.125 * log2(e): folded into Q at projection time
#define DEFER_THR 8.0f         // T13: log2-domain defer-max threshold (P <= 2^8)

static __device__ __forceinline__ unsigned pkbf(float x, float y) {
    v2bf t; t[0] = (bf16)x; t[1] = (bf16)y;
    return __builtin_bit_cast(unsigned, t);
}

// global -> LDS direct DMA, 16 B per lane. LDS dest must be wave-uniform base
// (HW adds lane*16); global src is per-lane.
static __device__ __forceinline__ void gld16(const bf16* g, const bf16* l) {
    __builtin_amdgcn_global_load_lds((const __attribute__((address_space(1))) void*)g,
                                     (__attribute__((address_space(3))) void*)l, 16, 0, 0);
}

// ---------------------------------------------------------------------------
// One-shot f32 -> bf16 conversion. Layout: xb[4096*1024], wqkvb[1536*1024]
// (Wq rows 0..1023, Wk rows 1024..1279, Wv rows 1280..1535), wob[1024*1024].
// ---------------------------------------------------------------------------
__global__ void convert_all(const float* __restrict__ x, const float* __restrict__ wq,
                            const float* __restrict__ wk, const float* __restrict__ wv,
                            const float* __restrict__ wo,
                            bf16* __restrict__ xb, bf16* __restrict__ wqkvb,
                            bf16* __restrict__ wob) {
    int i = (blockIdx.x * 256 + threadIdx.x) * 4;
    const float* src;
    bf16* dst;
    if (i < 4194304)      { src = x  + i;             dst = xb    + i; }
    else if (i < 5242880) { src = wq + (i - 4194304); dst = wqkvb + (i - 4194304); }
    else if (i < 5505024) { src = wk + (i - 5242880); dst = wqkvb + 1048576 + (i - 5242880); }
    else if (i < 5767168) { src = wv + (i - 5505024); dst = wqkvb + 1310720 + (i - 5505024); }
    else                  { src = wo + (i - 5767168); dst = wob   + (i - 5767168); }
    f32x4 v = *(const f32x4*)src;
    v4bf r;
#pragma unroll
    for (int j = 0; j < 4; j++) r[j] = (bf16)v[j];
    *(v4bf*)dst = r;
}

// ---------------------------------------------------------------------------
// Fused QKV projection (r8-proven config): C[4096][1536] = x @ [Wq;Wk;Wv]^T,
// 128x128 tiles, 512 threads, gload_lds width-16 double-buffered linear LDS,
// pre-swizzled global source + XOR'd ds_read (both-sides swizzle).
// Epilogue: Q (+RoPE, pre-scaled SCL2) -> Qb, K (+RoPE) -> Kb, V -> Vtg^T.
// ---------------------------------------------------------------------------
__global__ __launch_bounds__(512) void gemm_qkv(const bf16* __restrict__ A,
                                                const bf16* __restrict__ W,
                                                bf16* __restrict__ Qb,
                                                bf16* __restrict__ Kb,
                                                bf16* __restrict__ Vtg,
                                                const int* __restrict__ tp) {
    __shared__ bf16 As[2][128][64];
    __shared__ bf16 Bs[2][128][64];
    const int K = 1024;
    const int tid = threadIdx.x;
    const int w = tid >> 6, lane = tid & 63;
    const int quad = lane >> 4, l16 = lane & 15;
    const int wm = (w & 1) * 64, wn = (w >> 1) * 32;
    const int bm = blockIdx.x * 128, bn = blockIdx.y * 128;

    const int srow = lane >> 3;                         // 0..7
    const int scol = ((lane & 7) ^ srow) << 3;          // pre-swizzled source chunk

    f32x4 acc[4][2];
#pragma unroll
    for (int mf = 0; mf < 4; mf++)
#pragma unroll
        for (int nf = 0; nf < 2; nf++) acc[mf][nf] = (f32x4){0.f, 0.f, 0.f, 0.f};

#define QKV_STAGE(buf, ktt)                                                        \
    do {                                                                           \
        const bf16* ga = &A[(size_t)(bm + (w << 3) + srow) * 1024 + (ktt) + scol]; \
        const bf16* gb = &W[(size_t)(bn + (w << 3) + srow) * 1024 + (ktt) + scol]; \
        gld16(ga,             &As[buf][(w << 3)][0]);                              \
        gld16(ga + 64 * 1024, &As[buf][64 + (w << 3)][0]);                         \
        gld16(gb,             &Bs[buf][(w << 3)][0]);                              \
        gld16(gb + 64 * 1024, &Bs[buf][64 + (w << 3)][0]);                         \
    } while (0)

    QKV_STAGE(0, 0);
    __syncthreads();   // drains vmcnt: buffer 0 ready

    int cur = 0;
    for (int kt = 0; kt < K; kt += 64) {
        const bool more = (kt + 64) < K;
        if (more) QKV_STAGE(cur ^ 1, kt + 64);
#pragma unroll
        for (int kf = 0; kf < 2; kf++) {
            v8bf a[4], b[2];
#pragma unroll
            for (int mf = 0; mf < 4; mf++)
                a[mf] = *(v8bf*)&As[cur][wm + mf * 16 + l16][(((kf << 2) + quad) ^ (l16 & 7)) << 3];
#pragma unroll
            for (int nf = 0; nf < 2; nf++)
                b[nf] = *(v8bf*)&Bs[cur][wn + nf * 16 + l16][(((kf << 2) + quad) ^ (l16 & 7)) << 3];
#pragma unroll
            for (int mf = 0; mf < 4; mf++)
#pragma unroll
                for (int nf = 0; nf < 2; nf++)
                    acc[mf][nf] = __builtin_amdgcn_mfma_f32_16x16x32_bf16(a[mf], b[nf], acc[mf][nf], 0, 0, 0);
        }
        __syncthreads();
        cur ^= 1;
    }
#undef QKV_STAGE

    if (bn < 1024) {          // ---- Q region: RoPE + SCL2 pre-scale, store Qb ----
#pragma unroll
        for (int mf = 0; mf < 4; mf++) {
            int pos_[4];
#pragma unroll
            for (int r = 0; r < 4; r++) pos_[r] = tp[bm + wm + mf * 16 + quad * 4 + r];
#pragma unroll
            for (int nf = 0; nf < 2; nf++) {
                const int col = bn + wn + nf * 16 + l16;
                float fr = __expf(-(float)((col & 63) & ~1) * LN1E4_64);
#pragma unroll
                for (int r = 0; r < 4; r++) {
                    float v = acc[mf][nf][r];
                    float sn, cs;
                    __sincosf((float)pos_[r] * fr, &sn, &cs);
                    float p = __shfl_xor(v, 1);
                    float res = (l16 & 1) ? (p * sn + v * cs) : (v * cs - p * sn);
                    int row = bm + wm + mf * 16 + quad * 4 + r;
                    Qb[(size_t)row * DMODEL + col] = (bf16)(res * SCL2);
                }
            }
        }
    } else if (bn < 1280) {   // ---- K region: RoPE, store Kb[row][kcol] ----
#pragma unroll
        for (int mf = 0; mf < 4; mf++) {
            int pos_[4];
#pragma unroll
            for (int r = 0; r < 4; r++) pos_[r] = tp[bm + wm + mf * 16 + quad * 4 + r];
#pragma unroll
            for (int nf = 0; nf < 2; nf++) {
                const int kcol = bn - 1024 + wn + nf * 16 + l16;
                float fr = __expf(-(float)((kcol & 63) & ~1) * LN1E4_64);
#pragma unroll
                for (int r = 0; r < 4; r++) {
                    float v = acc[mf][nf][r];
                    float sn, cs;
                    __sincosf((float)pos_[r] * fr, &sn, &cs);
                    float p = __shfl_xor(v, 1);
                    float res = (l16 & 1) ? (p * sn + v * cs) : (v * cs - p * sn);
                    int row = bm + wm + mf * 16 + quad * 4 + r;
                    Kb[(size_t)row * 256 + kcol] = (bf16)res;
                }
            }
        }
    } else {                  // ---- V region: transposed store Vtg[vcol][row] ----
#pragma unroll
        for (int mf = 0; mf < 4; mf++)
#pragma unroll
            for (int nf = 0; nf < 2; nf++) {
                v4bf pk;
#pragma unroll
                for (int r = 0; r < 4; r++) pk[r] = (bf16)acc[mf][nf][r];
                int vcol = bn - 1280 + wn + nf * 16 + l16;
                int row = bm + wm + mf * 16 + quad * 4;
                *(v4bf*)&Vtg[(size_t)vcol * L_SEQ + row] = pk;
            }
    }
}

// ---------------------------------------------------------------------------
// Output projection (r8-proven config): out[4096][1024] = Attn @ Wo^T, f32.
// 128x128 tiles, 512 threads, same gload_lds + swizzle engine.
// ---------------------------------------------------------------------------
__global__ __launch_bounds__(512) void gemm_out(const bf16* __restrict__ A,
                                                const bf16* __restrict__ W,
                                                float* __restrict__ C) {
    __shared__ bf16 As[2][128][64];
    __shared__ bf16 Bs[2][128][64];
    const int K = 1024, N = 1024;
    const int tid = threadIdx.x;
    const int w = tid >> 6, lane = tid & 63;
    const int quad = lane >> 4, l16 = lane & 15;
    const int wm = (w & 1) * 64, wn = (w >> 1) * 32;
    const int bm = blockIdx.x * 128, bn = blockIdx.y * 128;

    const int srow = lane >> 3;
    const int scol = ((lane & 7) ^ srow) << 3;

    f32x4 acc[4][2];
#pragma unroll
    for (int mf = 0; mf < 4; mf++)
#pragma unroll
        for (int nf = 0; nf < 2; nf++) acc[mf][nf] = (f32x4){0.f, 0.f, 0.f, 0.f};

#define OUT_STAGE(buf, ktt)                                                        \
    do {                                                                           \
        const bf16* ga = &A[(size_t)(bm + (w << 3) + srow) * 1024 + (ktt) + scol]; \
        const bf16* gb = &W[(size_t)(bn + (w << 3) + srow) * 1024 + (ktt) + scol]; \
        gld16(ga,             &As[buf][(w << 3)][0]);                              \
        gld16(ga + 64 * 1024, &As[buf][64 + (w << 3)][0]);                         \
        gld16(gb,             &Bs[buf][(w << 3)][0]);                              \
        gld16(gb + 64 * 1024, &Bs[buf][64 + (w << 3)][0]);                         \
    } while (0)

    OUT_STAGE(0, 0);
    __syncthreads();

    int cur = 0;
    for (int kt = 0; kt < K; kt += 64) {
        const bool more = (kt + 64) < K;
        if (more) OUT_STAGE(cur ^ 1, kt + 64);
#pragma unroll
        for (int kf = 0; kf < 2; kf++) {
            v8bf a[4], b[2];
#pragma unroll
            for (int mf = 0; mf < 4; mf++)
                a[mf] = *(v8bf*)&As[cur][wm + mf * 16 + l16][(((kf << 2) + quad) ^ (l16 & 7)) << 3];
#pragma unroll
            for (int nf = 0; nf < 2; nf++)
                b[nf] = *(v8bf*)&Bs[cur][wn + nf * 16 + l16][(((kf << 2) + quad) ^ (l16 & 7)) << 3];
#pragma unroll
            for (int mf = 0; mf < 4; mf++)
#pragma unroll
                for (int nf = 0; nf < 2; nf++)
                    acc[mf][nf] = __builtin_amdgcn_mfma_f32_16x16x32_bf16(a[mf], b[nf], acc[mf][nf], 0, 0, 0);
        }
        __syncthreads();
        cur ^= 1;
    }
#undef OUT_STAGE

#pragma unroll
    for (int mf = 0; mf < 4; mf++)
#pragma unroll
        for (int nf = 0; nf < 2; nf++)
#pragma unroll
            for (int r = 0; r < 4; r++) {
                int row = bm + wm + mf * 16 + quad * 4 + r;
                int col = bn + wn + nf * 16 + l16;
                C[(size_t)row * N + col] = acc[mf][nf][r];
            }
}

// ---------------------------------------------------------------------------
// Flash v14: NO split-K, NO combine. Block (h, bx) runs TWO FULL row-blocks
// sequentially: qb = bx (tiles [0..bx]) then qb = 31-bx (tiles [0..31-bx]) --
// 33 tiles per block, perfectly leveled, same 16896 total tiles as v12.
// Core is v12's verified per-wave structure (swapped 32x32, Q pre-scaled,
// defer-max, l-via-MFMA, XCD-local h on blockIdx.x). Since no row is split,
// the epilogue normalizes in-register (l is lane-local in the O^T layout)
// and writes FINAL attn -> Attn. Eliminates combine + ML + partial traffic.
// ---------------------------------------------------------------------------
__global__ __launch_bounds__(256, 2) void flash14(const bf16* __restrict__ Q,
                                                  const bf16* __restrict__ Kb,
                                                  const bf16* __restrict__ Vtg,
                                                  bf16* __restrict__ Attn) {
    __shared__ bf16 Ks[128][68];
    __shared__ bf16 Vt[64][132];
    const int h = blockIdx.x, kvh = h >> 2;      // same-head blocks -> same XCD
    const int bx = blockIdx.y;
    const int tid = threadIdx.x;
    const int w = tid >> 6, lane = tid & 63;
    const int l32 = lane & 31, hi = lane >> 5;
    const int krow = tid >> 1, kcb = (tid & 1) * 32;
    const int vr = tid >> 2, vcb = (tid & 3) * 32;

    v8bf ones;
#pragma unroll
    for (int j = 0; j < 8; j++) ones[j] = (bf16)1.0f;

    for (int p = 0; p < 2; p++) {
        const int qb = p ? (31 - bx) : bx;
        const int k1 = qb + 1;                   // full pass: tiles [0, qb]

        const int qrow = qb * 128 + w * 32 + l32;
        v8bf qf[4];
#pragma unroll
        for (int d16 = 0; d16 < 4; d16++)
            qf[d16] = *(const v8bf*)&Q[(size_t)qrow * DMODEL + h * DH + d16 * 16 + hi * 8];

        f32x16 oaccT[2], lacc;
#pragma unroll
        for (int d = 0; d < 2; d++)
#pragma unroll
            for (int r = 0; r < 16; r++) oaccT[d][r] = 0.f;
#pragma unroll
        for (int r = 0; r < 16; r++) lacc[r] = 0.f;
        float m_i = NEG_BIG;

        v8bf kreg[4], vreg[4];
        {   // stage tile 0
            const bf16* ks = &Kb[(size_t)krow * 256 + kvh * DH + kcb];
            const bf16* vs = &Vtg[(size_t)(kvh * DH + vr) * L_SEQ + vcb];
#pragma unroll
            for (int u = 0; u < 4; u++) { kreg[u] = *(const v8bf*)&ks[8 * u]; vreg[u] = *(const v8bf*)&vs[8 * u]; }
            __syncthreads();   // prior piece's LDS reads (epilogue/QK) complete
#pragma unroll
            for (int u = 0; u < 4; u++) { *(v8bf*)&Ks[krow][kcb + 8 * u] = kreg[u]; *(v8bf*)&Vt[vr][vcb + 8 * u] = vreg[u]; }
        }

        for (int kb = 0; kb < k1; kb++) {
            __syncthreads();
            if (kb + 1 < k1) {
                const bf16* ks = &Kb[(size_t)((kb + 1) * 128 + krow) * 256 + kvh * DH + kcb];
                const bf16* vs = &Vtg[(size_t)(kvh * DH + vr) * L_SEQ + (kb + 1) * 128 + vcb];
#pragma unroll
                for (int u = 0; u < 4; u++) { kreg[u] = *(const v8bf*)&ks[8 * u]; vreg[u] = *(const v8bf*)&vs[8 * u]; }
            }

            // ---- QK^T (swapped): s[n] = S^T[key=n*32+...][q=lane&31] ----
            f32x16 s[4];
            __builtin_amdgcn_s_setprio(1);
#pragma unroll
            for (int n = 0; n < 4; n++) {
#pragma unroll
                for (int r = 0; r < 16; r++) s[n][r] = 0.f;
#pragma unroll
                for (int d16 = 0; d16 < 4; d16++) {
                    v8bf av = *(v8bf*)&Ks[n * 32 + l32][d16 * 16 + hi * 8];
                    s[n] = __builtin_amdgcn_mfma_f32_32x32x16_bf16(av, qf[d16], s[n], 0, 0, 0);
                }
            }
            __builtin_amdgcn_s_setprio(0);

            // ---- causal mask on diag tile only (scale folded into Q) ----
            if (kb == qb) {
#pragma unroll
                for (int n = 0; n < 4; n++) {
                    int kbase = kb * 128 + n * 32 + 4 * hi;
#pragma unroll
                    for (int r = 0; r < 16; r++) {
                        int key = kbase + (r & 3) + 8 * (r >> 2);
                        if (key > qrow) s[n][r] = NEG_BIG;
                    }
                }
            }

            // ---- online softmax: per-lane max3 reduce + one cross-half shuffle ----
            float mx = NEG_BIG;
#pragma unroll
            for (int n = 0; n < 4; n++)
#pragma unroll
                for (int r = 0; r < 16; r += 2)
                    mx = fmaxf(fmaxf(mx, s[n][r]), s[n][r + 1]);
            mx = fmaxf(mx, __shfl_xor(mx, 32));

            // defer-max: only rescale when the tile max materially grew
            if (!__all(mx <= m_i + DEFER_THR)) {
                float mnew = fmaxf(m_i, mx);
                float alpha = exp2f(m_i - mnew);
#pragma unroll
                for (int r = 0; r < 16; r++) lacc[r] *= alpha;
#pragma unroll
                for (int d = 0; d < 2; d++)
#pragma unroll
                    for (int r = 0; r < 16; r++) oaccT[d][r] *= alpha;
                m_i = mnew;
            }

#pragma unroll
            for (int n = 0; n < 4; n++)
#pragma unroll
                for (int r = 0; r < 16; r++)
                    s[n][r] = exp2f(s[n][r] - m_i);

            // ---- P pack + swap -> PV + l-sum via MFMA (no LDS round-trip) ----
            __builtin_amdgcn_s_setprio(1);
#pragma unroll
            for (int n = 0; n < 4; n++) {
#pragma unroll
                for (int u = 0; u < 2; u++) {
                    const int ro = u * 8;
                    unsigned a0 = pkbf(s[n][ro + 0], s[n][ro + 1]);
                    unsigned a1 = pkbf(s[n][ro + 2], s[n][ro + 3]);
                    unsigned b0 = pkbf(s[n][ro + 4], s[n][ro + 5]);
                    unsigned b1 = pkbf(s[n][ro + 6], s[n][ro + 7]);
#if __has_builtin(__builtin_amdgcn_permlane32_swap)
                    auto s0 = __builtin_amdgcn_permlane32_swap(a0, b0, false, false);
                    auto s1 = __builtin_amdgcn_permlane32_swap(a1, b1, false, false);
                    unsigned w0 = s0[0], w2 = s0[1], w1 = s1[0], w3 = s1[1];
#else
                    unsigned t0 = hi ? a0 : b0;
                    unsigned r0 = __shfl_xor(t0, 32);
                    unsigned w0 = hi ? r0 : a0, w2 = hi ? b0 : r0;
                    unsigned t1 = hi ? a1 : b1;
                    unsigned r1 = __shfl_xor(t1, 32);
                    unsigned w1 = hi ? r1 : a1, w3 = hi ? b1 : r1;
#endif
                    union { unsigned uu[4]; v8bf v; } pf;
                    pf.uu[0] = w0; pf.uu[1] = w1; pf.uu[2] = w2; pf.uu[3] = w3;
                    const int t = n * 2 + u;
#pragma unroll
                    for (int dblk = 0; dblk < 2; dblk++) {
                        v8bf av = *(v8bf*)&Vt[dblk * 32 + l32][t * 16 + hi * 8];
                        oaccT[dblk] = __builtin_amdgcn_mfma_f32_32x32x16_bf16(av, pf.v, oaccT[dblk], 0, 0, 0);
                    }
                    lacc = __builtin_amdgcn_mfma_f32_32x32x16_bf16(ones, pf.v, lacc, 0, 0, 0);
                }
            }
            __builtin_amdgcn_s_setprio(0);

            __syncthreads();
            if (kb + 1 < k1) {
#pragma unroll
                for (int u = 0; u < 4; u++) { *(v8bf*)&Ks[krow][kcb + 8 * u] = kreg[u]; *(v8bf*)&Vt[vr][vcb + 8 * u] = vreg[u]; }
            }
        }

        // ---- epilogue: normalize (l lane-local) + transpose via Ks + store ----
        const float linv = 1.f / lacc[0];
#pragma unroll
        for (int dblk = 0; dblk < 2; dblk++)
#pragma unroll
            for (int r = 0; r < 16; r++) {
                int d = dblk * 32 + (r & 3) + 8 * (r >> 2) + 4 * hi;
                Ks[w * 32 + l32][d] = (bf16)(oaccT[dblk][r] * linv);
            }
        asm volatile("s_waitcnt lgkmcnt(0)" ::: "memory");
        __builtin_amdgcn_sched_barrier(0);
#pragma unroll
        for (int ii = 0; ii < 4; ii++) {
            int cc = (lane & 1) * 32 + ii * 8;
            int rr = w * 32 + (lane >> 1);
            v8bf ov = *(v8bf*)&Ks[rr][cc];
            *(v8bf*)&Attn[(size_t)(qb * 128 + rr) * DMODEL + h * DH + cc] = ov;
        }
    }
}

// ---------------------------------------------------------------------------
extern "C" void kernel_launch(void* const* d_in, const int* in_sizes, int n_in,
                              void* d_out, int out_size, void* d_ws, size_t ws_size,
                              hipStream_t stream) {
    const float* x  = (const float*)d_in[0];
    const float* Wq = (const float*)d_in[1];
    const float* Wk = (const float*)d_in[2];
    const float* Wv = (const float*)d_in[3];
    const float* Wo = (const float*)d_in[4];
    const int*   tp = (const int*)d_in[5];
    float* out = (float*)d_out;

    bf16*  xb    = (bf16*)d_ws;               // 4,194,304
    bf16*  wqkvb = xb    + 4194304;           // 1,572,864
    bf16*  wob   = wqkvb + 1572864;           // 1,048,576
    bf16*  Qb    = wob   + 1048576;           // 4,194,304
    bf16*  Kb    = Qb    + 4194304;           // 1,048,576  [4096][256]
    bf16*  Vtg   = Kb    + 1048576;           // 1,048,576  [256][4096]
    bf16*  Attn  = Vtg   + 1048576;           // 4,194,304  final attn (bf16)

    convert_all<<<6656, 256, 0, stream>>>(x, Wq, Wk, Wv, Wo, xb, wqkvb, wob);
    gemm_qkv<<<dim3(32, 12), 512, 0, stream>>>(xb, wqkvb, Qb, Kb, Vtg, tp);
    flash14<<<dim3(NHEADS, 32), 256, 0, stream>>>(Qb, Kb, Vtg, Attn);
    gemm_out<<<dim3(32, 8), 512, 0, stream>>>(Attn, wob, out);
}

// Round 12
// 225.068 us; speedup vs baseline: 1.0642x; 1.0642x over previous
//
#include <hip/hip_runtime.h>
#include <hip/hip_bf16.h>
#include <math.h>

typedef __bf16 bf16;
typedef __bf16 v8bf __attribute__((ext_vector_type(8)));
typedef __bf16 v4bf __attribute__((ext_vector_type(4)));
typedef __bf16 v2bf __attribute__((ext_vector_type(2)));
typedef float f32x4 __attribute__((ext_vector_type(4)));
typedef float f32x16 __attribute__((ext_vector_type(16)));

#define L_SEQ 4096
#define DMODEL 1024
#define NHEADS 16
#define DH 64
#define NEG_BIG (-1e30f)
#define LN1E4_64 0.14391156f   // ln(10000)/64
#define SCL2 0.18033688f       // 0.125 * log2(e): folded into Q at projection time
#define DEFER_THR 8.0f         // T13: log2-domain defer-max threshold (P <= 2^8)

static __device__ __forceinline__ unsigned pkbf(float x, float y) {
    v2bf t; t[0] = (bf16)x; t[1] = (bf16)y;
    return __builtin_bit_cast(unsigned, t);
}

// global -> LDS direct DMA, 16 B per lane. LDS dest must be wave-uniform base
// (HW adds lane*16); global src is per-lane.
static __device__ __forceinline__ void gld16(const bf16* g, const bf16* l) {
    __builtin_amdgcn_global_load_lds((const __attribute__((address_space(1))) void*)g,
                                     (__attribute__((address_space(3))) void*)l, 16, 0, 0);
}

// ---------------------------------------------------------------------------
// One-shot f32 -> bf16 conversion. Layout: xb[4096*1024], wqkvb[1536*1024]
// (Wq rows 0..1023, Wk rows 1024..1279, Wv rows 1280..1535), wob[1024*1024].
// ---------------------------------------------------------------------------
__global__ void convert_all(const float* __restrict__ x, const float* __restrict__ wq,
                            const float* __restrict__ wk, const float* __restrict__ wv,
                            const float* __restrict__ wo,
                            bf16* __restrict__ xb, bf16* __restrict__ wqkvb,
                            bf16* __restrict__ wob) {
    int i = (blockIdx.x * 256 + threadIdx.x) * 4;
    const float* src;
    bf16* dst;
    if (i < 4194304)      { src = x  + i;             dst = xb    + i; }
    else if (i < 5242880) { src = wq + (i - 4194304); dst = wqkvb + (i - 4194304); }
    else if (i < 5505024) { src = wk + (i - 5242880); dst = wqkvb + 1048576 + (i - 5242880); }
    else if (i < 5767168) { src = wv + (i - 5505024); dst = wqkvb + 1310720 + (i - 5505024); }
    else                  { src = wo + (i - 5767168); dst = wob   + (i - 5767168); }
    f32x4 v = *(const f32x4*)src;
    v4bf r;
#pragma unroll
    for (int j = 0; j < 4; j++) r[j] = (bf16)v[j];
    *(v4bf*)dst = r;
}

// ---------------------------------------------------------------------------
// Fused QKV projection (r8-proven config): C[4096][1536] = x @ [Wq;Wk;Wv]^T,
// 128x128 tiles, 512 threads, gload_lds width-16 double-buffered linear LDS,
// pre-swizzled global source + XOR'd ds_read (both-sides swizzle).
// Epilogue: Q (+RoPE, pre-scaled SCL2) -> Qb, K (+RoPE) -> Kb, V -> Vtg^T.
// ---------------------------------------------------------------------------
__global__ __launch_bounds__(512) void gemm_qkv(const bf16* __restrict__ A,
                                                const bf16* __restrict__ W,
                                                bf16* __restrict__ Qb,
                                                bf16* __restrict__ Kb,
                                                bf16* __restrict__ Vtg,
                                                const int* __restrict__ tp) {
    __shared__ bf16 As[2][128][64];
    __shared__ bf16 Bs[2][128][64];
    const int K = 1024;
    const int tid = threadIdx.x;
    const int w = tid >> 6, lane = tid & 63;
    const int quad = lane >> 4, l16 = lane & 15;
    const int wm = (w & 1) * 64, wn = (w >> 1) * 32;
    const int bm = blockIdx.x * 128, bn = blockIdx.y * 128;

    const int srow = lane >> 3;                         // 0..7
    const int scol = ((lane & 7) ^ srow) << 3;          // pre-swizzled source chunk

    f32x4 acc[4][2];
#pragma unroll
    for (int mf = 0; mf < 4; mf++)
#pragma unroll
        for (int nf = 0; nf < 2; nf++) acc[mf][nf] = (f32x4){0.f, 0.f, 0.f, 0.f};

#define QKV_STAGE(buf, ktt)                                                        \
    do {                                                                           \
        const bf16* ga = &A[(size_t)(bm + (w << 3) + srow) * 1024 + (ktt) + scol]; \
        const bf16* gb = &W[(size_t)(bn + (w << 3) + srow) * 1024 + (ktt) + scol]; \
        gld16(ga,             &As[buf][(w << 3)][0]);                              \
        gld16(ga + 64 * 1024, &As[buf][64 + (w << 3)][0]);                         \
        gld16(gb,             &Bs[buf][(w << 3)][0]);                              \
        gld16(gb + 64 * 1024, &Bs[buf][64 + (w << 3)][0]);                         \
    } while (0)

    QKV_STAGE(0, 0);
    __syncthreads();   // drains vmcnt: buffer 0 ready

    int cur = 0;
    for (int kt = 0; kt < K; kt += 64) {
        const bool more = (kt + 64) < K;
        if (more) QKV_STAGE(cur ^ 1, kt + 64);
#pragma unroll
        for (int kf = 0; kf < 2; kf++) {
            v8bf a[4], b[2];
#pragma unroll
            for (int mf = 0; mf < 4; mf++)
                a[mf] = *(v8bf*)&As[cur][wm + mf * 16 + l16][(((kf << 2) + quad) ^ (l16 & 7)) << 3];
#pragma unroll
            for (int nf = 0; nf < 2; nf++)
                b[nf] = *(v8bf*)&Bs[cur][wn + nf * 16 + l16][(((kf << 2) + quad) ^ (l16 & 7)) << 3];
#pragma unroll
            for (int mf = 0; mf < 4; mf++)
#pragma unroll
                for (int nf = 0; nf < 2; nf++)
                    acc[mf][nf] = __builtin_amdgcn_mfma_f32_16x16x32_bf16(a[mf], b[nf], acc[mf][nf], 0, 0, 0);
        }
        __syncthreads();
        cur ^= 1;
    }
#undef QKV_STAGE

    if (bn < 1024) {          // ---- Q region: RoPE + SCL2 pre-scale, store Qb ----
#pragma unroll
        for (int mf = 0; mf < 4; mf++) {
            int pos_[4];
#pragma unroll
            for (int r = 0; r < 4; r++) pos_[r] = tp[bm + wm + mf * 16 + quad * 4 + r];
#pragma unroll
            for (int nf = 0; nf < 2; nf++) {
                const int col = bn + wn + nf * 16 + l16;
                float fr = __expf(-(float)((col & 63) & ~1) * LN1E4_64);
#pragma unroll
                for (int r = 0; r < 4; r++) {
                    float v = acc[mf][nf][r];
                    float sn, cs;
                    __sincosf((float)pos_[r] * fr, &sn, &cs);
                    float p = __shfl_xor(v, 1);
                    float res = (l16 & 1) ? (p * sn + v * cs) : (v * cs - p * sn);
                    int row = bm + wm + mf * 16 + quad * 4 + r;
                    Qb[(size_t)row * DMODEL + col] = (bf16)(res * SCL2);
                }
            }
        }
    } else if (bn < 1280) {   // ---- K region: RoPE, store Kb[row][kcol] ----
#pragma unroll
        for (int mf = 0; mf < 4; mf++) {
            int pos_[4];
#pragma unroll
            for (int r = 0; r < 4; r++) pos_[r] = tp[bm + wm + mf * 16 + quad * 4 + r];
#pragma unroll
            for (int nf = 0; nf < 2; nf++) {
                const int kcol = bn - 1024 + wn + nf * 16 + l16;
                float fr = __expf(-(float)((kcol & 63) & ~1) * LN1E4_64);
#pragma unroll
                for (int r = 0; r < 4; r++) {
                    float v = acc[mf][nf][r];
                    float sn, cs;
                    __sincosf((float)pos_[r] * fr, &sn, &cs);
                    float p = __shfl_xor(v, 1);
                    float res = (l16 & 1) ? (p * sn + v * cs) : (v * cs - p * sn);
                    int row = bm + wm + mf * 16 + quad * 4 + r;
                    Kb[(size_t)row * 256 + kcol] = (bf16)res;
                }
            }
        }
    } else {                  // ---- V region: transposed store Vtg[vcol][row] ----
#pragma unroll
        for (int mf = 0; mf < 4; mf++)
#pragma unroll
            for (int nf = 0; nf < 2; nf++) {
                v4bf pk;
#pragma unroll
                for (int r = 0; r < 4; r++) pk[r] = (bf16)acc[mf][nf][r];
                int vcol = bn - 1280 + wn + nf * 16 + l16;
                int row = bm + wm + mf * 16 + quad * 4;
                *(v4bf*)&Vtg[(size_t)vcol * L_SEQ + row] = pk;
            }
    }
}

// ---------------------------------------------------------------------------
// Output projection (r8-proven config): out[4096][1024] = Attn @ Wo^T, f32.
// 128x128 tiles, 512 threads, same gload_lds + swizzle engine.
// ---------------------------------------------------------------------------
__global__ __launch_bounds__(512) void gemm_out(const bf16* __restrict__ A,
                                                const bf16* __restrict__ W,
                                                float* __restrict__ C) {
    __shared__ bf16 As[2][128][64];
    __shared__ bf16 Bs[2][128][64];
    const int K = 1024, N = 1024;
    const int tid = threadIdx.x;
    const int w = tid >> 6, lane = tid & 63;
    const int quad = lane >> 4, l16 = lane & 15;
    const int wm = (w & 1) * 64, wn = (w >> 1) * 32;
    const int bm = blockIdx.x * 128, bn = blockIdx.y * 128;

    const int srow = lane >> 3;
    const int scol = ((lane & 7) ^ srow) << 3;

    f32x4 acc[4][2];
#pragma unroll
    for (int mf = 0; mf < 4; mf++)
#pragma unroll
        for (int nf = 0; nf < 2; nf++) acc[mf][nf] = (f32x4){0.f, 0.f, 0.f, 0.f};

#define OUT_STAGE(buf, ktt)                                                        \
    do {                                                                           \
        const bf16* ga = &A[(size_t)(bm + (w << 3) + srow) * 1024 + (ktt) + scol]; \
        const bf16* gb = &W[(size_t)(bn + (w << 3) + srow) * 1024 + (ktt) + scol]; \
        gld16(ga,             &As[buf][(w << 3)][0]);                              \
        gld16(ga + 64 * 1024, &As[buf][64 + (w << 3)][0]);                         \
        gld16(gb,             &Bs[buf][(w << 3)][0]);                              \
        gld16(gb + 64 * 1024, &Bs[buf][64 + (w << 3)][0]);                         \
    } while (0)

    OUT_STAGE(0, 0);
    __syncthreads();

    int cur = 0;
    for (int kt = 0; kt < K; kt += 64) {
        const bool more = (kt + 64) < K;
        if (more) OUT_STAGE(cur ^ 1, kt + 64);
#pragma unroll
        for (int kf = 0; kf < 2; kf++) {
            v8bf a[4], b[2];
#pragma unroll
            for (int mf = 0; mf < 4; mf++)
                a[mf] = *(v8bf*)&As[cur][wm + mf * 16 + l16][(((kf << 2) + quad) ^ (l16 & 7)) << 3];
#pragma unroll
            for (int nf = 0; nf < 2; nf++)
                b[nf] = *(v8bf*)&Bs[cur][wn + nf * 16 + l16][(((kf << 2) + quad) ^ (l16 & 7)) << 3];
#pragma unroll
            for (int mf = 0; mf < 4; mf++)
#pragma unroll
                for (int nf = 0; nf < 2; nf++)
                    acc[mf][nf] = __builtin_amdgcn_mfma_f32_16x16x32_bf16(a[mf], b[nf], acc[mf][nf], 0, 0, 0);
        }
        __syncthreads();
        cur ^= 1;
    }
#undef OUT_STAGE

#pragma unroll
    for (int mf = 0; mf < 4; mf++)
#pragma unroll
        for (int nf = 0; nf < 2; nf++)
#pragma unroll
            for (int r = 0; r < 4; r++) {
                int row = bm + wm + mf * 16 + quad * 4 + r;
                int col = bn + wn + nf * 16 + l16;
                C[(size_t)row * N + col] = acc[mf][nf][r];
            }
}

// ---------------------------------------------------------------------------
// Flash v15: NO split-K, NO combine, ONE full row-block per block.
// Grid (16, 32): qb = (i<16) ? 31-i : i-16. Each qb appears exactly ONCE
// (v14's bug: its pairing covered every qb twice -> 2x work, 154us).
// Blocks (h,i) and (h,i+16) differ by 256 in linear id -> any modular
// block->CU assignment with period 256 co-locates them; work sums to
// (32-i)+(i+1) = 33 tiles per CU pair — leveled like v12. Heavy halves
// (i<16) dispatch first. XCD-local (blockIdx.x = h).
// Epilogue normalizes in-register (l lane-local in O^T layout) and writes
// FINAL Attn. Eliminates combine kernel + ML + half the partial traffic.
// ---------------------------------------------------------------------------
__global__ __launch_bounds__(256, 2) void flash15(const bf16* __restrict__ Q,
                                                  const bf16* __restrict__ Kb,
                                                  const bf16* __restrict__ Vtg,
                                                  bf16* __restrict__ Attn) {
    __shared__ bf16 Ks[128][68];
    __shared__ bf16 Vt[64][132];
    const int h = blockIdx.x, kvh = h >> 2;      // same-head blocks -> same XCD
    const int i = blockIdx.y;
    const int qb = (i < 16) ? (31 - i) : (i - 16);
    const int tid = threadIdx.x;
    const int w = tid >> 6, lane = tid & 63;
    const int l32 = lane & 31, hi = lane >> 5;
    const int krow = tid >> 1, kcb = (tid & 1) * 32;
    const int vr = tid >> 2, vcb = (tid & 3) * 32;

    const int k1 = qb + 1;                       // full causal range [0, qb]

    v8bf ones;
#pragma unroll
    for (int j = 0; j < 8; j++) ones[j] = (bf16)1.0f;

    const int qrow = qb * 128 + w * 32 + l32;
    v8bf qf[4];
#pragma unroll
    for (int d16 = 0; d16 < 4; d16++)
        qf[d16] = *(const v8bf*)&Q[(size_t)qrow * DMODEL + h * DH + d16 * 16 + hi * 8];

    f32x16 oaccT[2], lacc;
#pragma unroll
    for (int d = 0; d < 2; d++)
#pragma unroll
        for (int r = 0; r < 16; r++) oaccT[d][r] = 0.f;
#pragma unroll
    for (int r = 0; r < 16; r++) lacc[r] = 0.f;
    float m_i = NEG_BIG;

    v8bf kreg[4], vreg[4];
    {   // stage tile 0
        const bf16* ks = &Kb[(size_t)krow * 256 + kvh * DH + kcb];
        const bf16* vs = &Vtg[(size_t)(kvh * DH + vr) * L_SEQ + vcb];
#pragma unroll
        for (int u = 0; u < 4; u++) { kreg[u] = *(const v8bf*)&ks[8 * u]; vreg[u] = *(const v8bf*)&vs[8 * u]; }
#pragma unroll
        for (int u = 0; u < 4; u++) { *(v8bf*)&Ks[krow][kcb + 8 * u] = kreg[u]; *(v8bf*)&Vt[vr][vcb + 8 * u] = vreg[u]; }
    }

    for (int kb = 0; kb < k1; kb++) {
        __syncthreads();
        if (kb + 1 < k1) {
            const bf16* ks = &Kb[(size_t)((kb + 1) * 128 + krow) * 256 + kvh * DH + kcb];
            const bf16* vs = &Vtg[(size_t)(kvh * DH + vr) * L_SEQ + (kb + 1) * 128 + vcb];
#pragma unroll
            for (int u = 0; u < 4; u++) { kreg[u] = *(const v8bf*)&ks[8 * u]; vreg[u] = *(const v8bf*)&vs[8 * u]; }
        }

        // ---- QK^T (swapped): s[n] = S^T[key=n*32+...][q=lane&31] ----
        f32x16 s[4];
        __builtin_amdgcn_s_setprio(1);
#pragma unroll
        for (int n = 0; n < 4; n++) {
#pragma unroll
            for (int r = 0; r < 16; r++) s[n][r] = 0.f;
#pragma unroll
            for (int d16 = 0; d16 < 4; d16++) {
                v8bf av = *(v8bf*)&Ks[n * 32 + l32][d16 * 16 + hi * 8];
                s[n] = __builtin_amdgcn_mfma_f32_32x32x16_bf16(av, qf[d16], s[n], 0, 0, 0);
            }
        }
        __builtin_amdgcn_s_setprio(0);

        // ---- causal mask on diag tile only (scale folded into Q) ----
        if (kb == qb) {
#pragma unroll
            for (int n = 0; n < 4; n++) {
                int kbase = kb * 128 + n * 32 + 4 * hi;
#pragma unroll
                for (int r = 0; r < 16; r++) {
                    int key = kbase + (r & 3) + 8 * (r >> 2);
                    if (key > qrow) s[n][r] = NEG_BIG;
                }
            }
        }

        // ---- online softmax: per-lane max3 reduce + one cross-half shuffle ----
        float mx = NEG_BIG;
#pragma unroll
        for (int n = 0; n < 4; n++)
#pragma unroll
            for (int r = 0; r < 16; r += 2)
                mx = fmaxf(fmaxf(mx, s[n][r]), s[n][r + 1]);
        mx = fmaxf(mx, __shfl_xor(mx, 32));

        // defer-max: only rescale when the tile max materially grew
        if (!__all(mx <= m_i + DEFER_THR)) {
            float mnew = fmaxf(m_i, mx);
            float alpha = exp2f(m_i - mnew);
#pragma unroll
            for (int r = 0; r < 16; r++) lacc[r] *= alpha;
#pragma unroll
            for (int d = 0; d < 2; d++)
#pragma unroll
                for (int r = 0; r < 16; r++) oaccT[d][r] *= alpha;
            m_i = mnew;
        }

#pragma unroll
        for (int n = 0; n < 4; n++)
#pragma unroll
            for (int r = 0; r < 16; r++)
                s[n][r] = exp2f(s[n][r] - m_i);

        // ---- P pack + swap -> PV + l-sum via MFMA (no LDS round-trip) ----
        __builtin_amdgcn_s_setprio(1);
#pragma unroll
        for (int n = 0; n < 4; n++) {
#pragma unroll
            for (int u = 0; u < 2; u++) {
                const int ro = u * 8;
                unsigned a0 = pkbf(s[n][ro + 0], s[n][ro + 1]);
                unsigned a1 = pkbf(s[n][ro + 2], s[n][ro + 3]);
                unsigned b0 = pkbf(s[n][ro + 4], s[n][ro + 5]);
                unsigned b1 = pkbf(s[n][ro + 6], s[n][ro + 7]);
#if __has_builtin(__builtin_amdgcn_permlane32_swap)
                auto s0 = __builtin_amdgcn_permlane32_swap(a0, b0, false, false);
                auto s1 = __builtin_amdgcn_permlane32_swap(a1, b1, false, false);
                unsigned w0 = s0[0], w2 = s0[1], w1 = s1[0], w3 = s1[1];
#else
                unsigned t0 = hi ? a0 : b0;
                unsigned r0 = __shfl_xor(t0, 32);
                unsigned w0 = hi ? r0 : a0, w2 = hi ? b0 : r0;
                unsigned t1 = hi ? a1 : b1;
                unsigned r1 = __shfl_xor(t1, 32);
                unsigned w1 = hi ? r1 : a1, w3 = hi ? b1 : r1;
#endif
                union { unsigned uu[4]; v8bf v; } pf;
                pf.uu[0] = w0; pf.uu[1] = w1; pf.uu[2] = w2; pf.uu[3] = w3;
                const int t = n * 2 + u;
#pragma unroll
                for (int dblk = 0; dblk < 2; dblk++) {
                    v8bf av = *(v8bf*)&Vt[dblk * 32 + l32][t * 16 + hi * 8];
                    oaccT[dblk] = __builtin_amdgcn_mfma_f32_32x32x16_bf16(av, pf.v, oaccT[dblk], 0, 0, 0);
                }
                lacc = __builtin_amdgcn_mfma_f32_32x32x16_bf16(ones, pf.v, lacc, 0, 0, 0);
            }
        }
        __builtin_amdgcn_s_setprio(0);

        __syncthreads();
        if (kb + 1 < k1) {
#pragma unroll
            for (int u = 0; u < 4; u++) { *(v8bf*)&Ks[krow][kcb + 8 * u] = kreg[u]; *(v8bf*)&Vt[vr][vcb + 8 * u] = vreg[u]; }
        }
    }

    // ---- epilogue: normalize (l lane-local) + transpose via Ks + store ----
    const float linv = 1.f / lacc[0];
#pragma unroll
    for (int dblk = 0; dblk < 2; dblk++)
#pragma unroll
        for (int r = 0; r < 16; r++) {
            int d = dblk * 32 + (r & 3) + 8 * (r >> 2) + 4 * hi;
            Ks[w * 32 + l32][d] = (bf16)(oaccT[dblk][r] * linv);
        }
    asm volatile("s_waitcnt lgkmcnt(0)" ::: "memory");
    __builtin_amdgcn_sched_barrier(0);
#pragma unroll
    for (int ii = 0; ii < 4; ii++) {
        int cc = (lane & 1) * 32 + ii * 8;
        int rr = w * 32 + (lane >> 1);
        v8bf ov = *(v8bf*)&Ks[rr][cc];
        *(v8bf*)&Attn[(size_t)(qb * 128 + rr) * DMODEL + h * DH + cc] = ov;
    }
}

// ---------------------------------------------------------------------------
extern "C" void kernel_launch(void* const* d_in, const int* in_sizes, int n_in,
                              void* d_out, int out_size, void* d_ws, size_t ws_size,
                              hipStream_t stream) {
    const float* x  = (const float*)d_in[0];
    const float* Wq = (const float*)d_in[1];
    const float* Wk = (const float*)d_in[2];
    const float* Wv = (const float*)d_in[3];
    const float* Wo = (const float*)d_in[4];
    const int*   tp = (const int*)d_in[5];
    float* out = (float*)d_out;

    bf16*  xb    = (bf16*)d_ws;               // 4,194,304
    bf16*  wqkvb = xb    + 4194304;           // 1,572,864
    bf16*  wob   = wqkvb + 1572864;           // 1,048,576
    bf16*  Qb    = wob   + 1048576;           // 4,194,304
    bf16*  Kb    = Qb    + 4194304;           // 1,048,576  [4096][256]
    bf16*  Vtg   = Kb    + 1048576;           // 1,048,576  [256][4096]
    bf16*  Attn  = Vtg   + 1048576;           // 4,194,304  final attn (bf16)

    convert_all<<<6656, 256, 0, stream>>>(x, Wq, Wk, Wv, Wo, xb, wqkvb, wob);
    gemm_qkv<<<dim3(32, 12), 512, 0, stream>>>(xb, wqkvb, Qb, Kb, Vtg, tp);
    flash15<<<dim3(NHEADS, 32), 256, 0, stream>>>(Qb, Kb, Vtg, Attn);
    gemm_out<<<dim3(32, 8), 512, 0, stream>>>(Attn, wob, out);
}

// Round 13
// 191.027 us; speedup vs baseline: 1.2539x; 1.1782x over previous
//
#include <hip/hip_runtime.h>
#include <hip/hip_bf16.h>
#include <math.h>

typedef __bf16 bf16;
typedef __bf16 v8bf __attribute__((ext_vector_type(8)));
typedef __bf16 v4bf __attribute__((ext_vector_type(4)));
typedef __bf16 v2bf __attribute__((ext_vector_type(2)));
typedef float f32x4 __attribute__((ext_vector_type(4)));
typedef float f32x16 __attribute__((ext_vector_type(16)));

#define L_SEQ 4096
#define DMODEL 1024
#define NHEADS 16
#define DH 64
#define NEG_BIG (-1e30f)
#define LN1E4_64 0.14391156f   // ln(10000)/64
#define SCL2 0.18033688f       // 0.125 * log2(e): folded into Q at projection time
#define DEFER_THR 8.0f         // T13: log2-domain defer-max threshold (P <= 2^8)

static __device__ __forceinline__ unsigned pkbf(float x, float y) {
    v2bf t; t[0] = (bf16)x; t[1] = (bf16)y;
    return __builtin_bit_cast(unsigned, t);
}

// global -> LDS direct DMA, 16 B per lane. LDS dest must be wave-uniform base
// (HW adds lane*16); global src is per-lane.
static __device__ __forceinline__ void gld16(const bf16* g, const bf16* l) {
    __builtin_amdgcn_global_load_lds((const __attribute__((address_space(1))) void*)g,
                                     (__attribute__((address_space(3))) void*)l, 16, 0, 0);
}

// ---------------------------------------------------------------------------
// One-shot f32 -> bf16 conversion. Layout: xb[4096*1024], wqkvb[1536*1024]
// (Wq rows 0..1023, Wk rows 1024..1279, Wv rows 1280..1535), wob[1024*1024].
// ---------------------------------------------------------------------------
__global__ void convert_all(const float* __restrict__ x, const float* __restrict__ wq,
                            const float* __restrict__ wk, const float* __restrict__ wv,
                            const float* __restrict__ wo,
                            bf16* __restrict__ xb, bf16* __restrict__ wqkvb,
                            bf16* __restrict__ wob) {
    int i = (blockIdx.x * 256 + threadIdx.x) * 4;
    const float* src;
    bf16* dst;
    if (i < 4194304)      { src = x  + i;             dst = xb    + i; }
    else if (i < 5242880) { src = wq + (i - 4194304); dst = wqkvb + (i - 4194304); }
    else if (i < 5505024) { src = wk + (i - 5242880); dst = wqkvb + 1048576 + (i - 5242880); }
    else if (i < 5767168) { src = wv + (i - 5505024); dst = wqkvb + 1310720 + (i - 5505024); }
    else                  { src = wo + (i - 5767168); dst = wob   + (i - 5767168); }
    f32x4 v = *(const f32x4*)src;
    v4bf r;
#pragma unroll
    for (int j = 0; j < 4; j++) r[j] = (bf16)v[j];
    *(v4bf*)dst = r;
}

// ---------------------------------------------------------------------------
// Fused QKV projection (r8-proven config): C[4096][1536] = x @ [Wq;Wk;Wv]^T,
// 128x128 tiles, 512 threads, gload_lds width-16 double-buffered linear LDS,
// pre-swizzled global source + XOR'd ds_read (both-sides swizzle).
// Epilogue: Q (+RoPE, pre-scaled SCL2) -> Qb, K (+RoPE) -> Kb, V -> Vtg^T.
// ---------------------------------------------------------------------------
__global__ __launch_bounds__(512) void gemm_qkv(const bf16* __restrict__ A,
                                                const bf16* __restrict__ W,
                                                bf16* __restrict__ Qb,
                                                bf16* __restrict__ Kb,
                                                bf16* __restrict__ Vtg,
                                                const int* __restrict__ tp) {
    __shared__ bf16 As[2][128][64];
    __shared__ bf16 Bs[2][128][64];
    const int K = 1024;
    const int tid = threadIdx.x;
    const int w = tid >> 6, lane = tid & 63;
    const int quad = lane >> 4, l16 = lane & 15;
    const int wm = (w & 1) * 64, wn = (w >> 1) * 32;
    const int bm = blockIdx.x * 128, bn = blockIdx.y * 128;

    const int srow = lane >> 3;                         // 0..7
    const int scol = ((lane & 7) ^ srow) << 3;          // pre-swizzled source chunk

    f32x4 acc[4][2];
#pragma unroll
    for (int mf = 0; mf < 4; mf++)
#pragma unroll
        for (int nf = 0; nf < 2; nf++) acc[mf][nf] = (f32x4){0.f, 0.f, 0.f, 0.f};

#define QKV_STAGE(buf, ktt)                                                        \
    do {                                                                           \
        const bf16* ga = &A[(size_t)(bm + (w << 3) + srow) * 1024 + (ktt) + scol]; \
        const bf16* gb = &W[(size_t)(bn + (w << 3) + srow) * 1024 + (ktt) + scol]; \
        gld16(ga,             &As[buf][(w << 3)][0]);                              \
        gld16(ga + 64 * 1024, &As[buf][64 + (w << 3)][0]);                         \
        gld16(gb,             &Bs[buf][(w << 3)][0]);                              \
        gld16(gb + 64 * 1024, &Bs[buf][64 + (w << 3)][0]);                         \
    } while (0)

    QKV_STAGE(0, 0);
    __syncthreads();   // drains vmcnt: buffer 0 ready

    int cur = 0;
    for (int kt = 0; kt < K; kt += 64) {
        const bool more = (kt + 64) < K;
        if (more) QKV_STAGE(cur ^ 1, kt + 64);
#pragma unroll
        for (int kf = 0; kf < 2; kf++) {
            v8bf a[4], b[2];
#pragma unroll
            for (int mf = 0; mf < 4; mf++)
                a[mf] = *(v8bf*)&As[cur][wm + mf * 16 + l16][(((kf << 2) + quad) ^ (l16 & 7)) << 3];
#pragma unroll
            for (int nf = 0; nf < 2; nf++)
                b[nf] = *(v8bf*)&Bs[cur][wn + nf * 16 + l16][(((kf << 2) + quad) ^ (l16 & 7)) << 3];
#pragma unroll
            for (int mf = 0; mf < 4; mf++)
#pragma unroll
                for (int nf = 0; nf < 2; nf++)
                    acc[mf][nf] = __builtin_amdgcn_mfma_f32_16x16x32_bf16(a[mf], b[nf], acc[mf][nf], 0, 0, 0);
        }
        __syncthreads();
        cur ^= 1;
    }
#undef QKV_STAGE

    if (bn < 1024) {          // ---- Q region: RoPE + SCL2 pre-scale, store Qb ----
#pragma unroll
        for (int mf = 0; mf < 4; mf++) {
            int pos_[4];
#pragma unroll
            for (int r = 0; r < 4; r++) pos_[r] = tp[bm + wm + mf * 16 + quad * 4 + r];
#pragma unroll
            for (int nf = 0; nf < 2; nf++) {
                const int col = bn + wn + nf * 16 + l16;
                float fr = __expf(-(float)((col & 63) & ~1) * LN1E4_64);
#pragma unroll
                for (int r = 0; r < 4; r++) {
                    float v = acc[mf][nf][r];
                    float sn, cs;
                    __sincosf((float)pos_[r] * fr, &sn, &cs);
                    float p = __shfl_xor(v, 1);
                    float res = (l16 & 1) ? (p * sn + v * cs) : (v * cs - p * sn);
                    int row = bm + wm + mf * 16 + quad * 4 + r;
                    Qb[(size_t)row * DMODEL + col] = (bf16)(res * SCL2);
                }
            }
        }
    } else if (bn < 1280) {   // ---- K region: RoPE, store Kb[row][kcol] ----
#pragma unroll
        for (int mf = 0; mf < 4; mf++) {
            int pos_[4];
#pragma unroll
            for (int r = 0; r < 4; r++) pos_[r] = tp[bm + wm + mf * 16 + quad * 4 + r];
#pragma unroll
            for (int nf = 0; nf < 2; nf++) {
                const int kcol = bn - 1024 + wn + nf * 16 + l16;
                float fr = __expf(-(float)((kcol & 63) & ~1) * LN1E4_64);
#pragma unroll
                for (int r = 0; r < 4; r++) {
                    float v = acc[mf][nf][r];
                    float sn, cs;
                    __sincosf((float)pos_[r] * fr, &sn, &cs);
                    float p = __shfl_xor(v, 1);
                    float res = (l16 & 1) ? (p * sn + v * cs) : (v * cs - p * sn);
                    int row = bm + wm + mf * 16 + quad * 4 + r;
                    Kb[(size_t)row * 256 + kcol] = (bf16)res;
                }
            }
        }
    } else {                  // ---- V region: transposed store Vtg[vcol][row] ----
#pragma unroll
        for (int mf = 0; mf < 4; mf++)
#pragma unroll
            for (int nf = 0; nf < 2; nf++) {
                v4bf pk;
#pragma unroll
                for (int r = 0; r < 4; r++) pk[r] = (bf16)acc[mf][nf][r];
                int vcol = bn - 1280 + wn + nf * 16 + l16;
                int row = bm + wm + mf * 16 + quad * 4;
                *(v4bf*)&Vtg[(size_t)vcol * L_SEQ + row] = pk;
            }
    }
}

// ---------------------------------------------------------------------------
// Output projection (r8-proven config): out[4096][1024] = Attn @ Wo^T, f32.
// 128x128 tiles, 512 threads, same gload_lds + swizzle engine.
// ---------------------------------------------------------------------------
__global__ __launch_bounds__(512) void gemm_out(const bf16* __restrict__ A,
                                                const bf16* __restrict__ W,
                                                float* __restrict__ C) {
    __shared__ bf16 As[2][128][64];
    __shared__ bf16 Bs[2][128][64];
    const int K = 1024, N = 1024;
    const int tid = threadIdx.x;
    const int w = tid >> 6, lane = tid & 63;
    const int quad = lane >> 4, l16 = lane & 15;
    const int wm = (w & 1) * 64, wn = (w >> 1) * 32;
    const int bm = blockIdx.x * 128, bn = blockIdx.y * 128;

    const int srow = lane >> 3;
    const int scol = ((lane & 7) ^ srow) << 3;

    f32x4 acc[4][2];
#pragma unroll
    for (int mf = 0; mf < 4; mf++)
#pragma unroll
        for (int nf = 0; nf < 2; nf++) acc[mf][nf] = (f32x4){0.f, 0.f, 0.f, 0.f};

#define OUT_STAGE(buf, ktt)                                                        \
    do {                                                                           \
        const bf16* ga = &A[(size_t)(bm + (w << 3) + srow) * 1024 + (ktt) + scol]; \
        const bf16* gb = &W[(size_t)(bn + (w << 3) + srow) * 1024 + (ktt) + scol]; \
        gld16(ga,             &As[buf][(w << 3)][0]);                              \
        gld16(ga + 64 * 1024, &As[buf][64 + (w << 3)][0]);                         \
        gld16(gb,             &Bs[buf][(w << 3)][0]);                              \
        gld16(gb + 64 * 1024, &Bs[buf][64 + (w << 3)][0]);                         \
    } while (0)

    OUT_STAGE(0, 0);
    __syncthreads();

    int cur = 0;
    for (int kt = 0; kt < K; kt += 64) {
        const bool more = (kt + 64) < K;
        if (more) OUT_STAGE(cur ^ 1, kt + 64);
#pragma unroll
        for (int kf = 0; kf < 2; kf++) {
            v8bf a[4], b[2];
#pragma unroll
            for (int mf = 0; mf < 4; mf++)
                a[mf] = *(v8bf*)&As[cur][wm + mf * 16 + l16][(((kf << 2) + quad) ^ (l16 & 7)) << 3];
#pragma unroll
            for (int nf = 0; nf < 2; nf++)
                b[nf] = *(v8bf*)&Bs[cur][wn + nf * 16 + l16][(((kf << 2) + quad) ^ (l16 & 7)) << 3];
#pragma unroll
            for (int mf = 0; mf < 4; mf++)
#pragma unroll
                for (int nf = 0; nf < 2; nf++)
                    acc[mf][nf] = __builtin_amdgcn_mfma_f32_16x16x32_bf16(a[mf], b[nf], acc[mf][nf], 0, 0, 0);
        }
        __syncthreads();
        cur ^= 1;
    }
#undef OUT_STAGE

#pragma unroll
    for (int mf = 0; mf < 4; mf++)
#pragma unroll
        for (int nf = 0; nf < 2; nf++)
#pragma unroll
            for (int r = 0; r < 4; r++) {
                int row = bm + wm + mf * 16 + quad * 4 + r;
                int col = bn + wn + nf * 16 + l16;
                C[(size_t)row * N + col] = acc[mf][nf][r];
            }
}

// ---------------------------------------------------------------------------
// Flash v16 = r8's flash12 with the l-sum reverted to v10's VALU form.
// (v10->v11 bundled the XCD grid [good: FETCH 24->12.6 MB] with l-via-MFMA
// [bad: serial 8-MFMA chain on a latency-bound kernel, flash 79.3->81.4].
// Keep the grid, drop the chain.) ONE leveled split-K piece per block,
// grid (16, 64): qb = 31-(i>>1), half = i&1. Swapped 32x32, Q pre-scaled,
// defer-max, max3 reduce, in-block leveling (16-17 tiles every block).
// ---------------------------------------------------------------------------
__global__ __launch_bounds__(256, 2) void flash16(const bf16* __restrict__ Q,
                                                  const bf16* __restrict__ Kb,
                                                  const bf16* __restrict__ Vtg,
                                                  bf16* __restrict__ O0,
                                                  bf16* __restrict__ O1,
                                                  float* __restrict__ ML) {
    __shared__ bf16 Ks[128][68];
    __shared__ bf16 Vt[64][132];
    const int h = blockIdx.x, kvh = h >> 2;      // same-head blocks -> same XCD
    const int i = blockIdx.y;
    const int qb = 31 - (i >> 1);
    const int half = i & 1;
    const int tid = threadIdx.x;
    const int w = tid >> 6, lane = tid & 63;
    const int l32 = lane & 31, hi = lane >> 5;
    const int krow = tid >> 1, kcb = (tid & 1) * 32;
    const int vr = tid >> 2, vcb = (tid & 3) * 32;

    const int T = qb + 1;
    const int k0 = half ? ((T + 1) >> 1) : 0;
    const int k1 = half ? T : ((T + 1) >> 1);
    bf16* Op = half ? O1 : O0;
    float* mlp = ML + (size_t)(half * NHEADS + h) * L_SEQ * 2;

    if (k0 >= k1) {   // empty piece (half=1, qb=0): zero partial
        for (int ii = tid; ii < 128 * 64; ii += 256) {
            int rr = ii >> 6, cc = ii & 63;
            Op[(size_t)(qb * 128 + rr) * DMODEL + h * DH + cc] = (bf16)0.f;
        }
        if (tid < 128) {
            mlp[(qb * 128 + tid) * 2 + 0] = NEG_BIG;
            mlp[(qb * 128 + tid) * 2 + 1] = 0.f;
        }
        return;
    }

    const int qrow = qb * 128 + w * 32 + l32;
    v8bf qf[4];
#pragma unroll
    for (int d16 = 0; d16 < 4; d16++)
        qf[d16] = *(const v8bf*)&Q[(size_t)qrow * DMODEL + h * DH + d16 * 16 + hi * 8];

    f32x16 oaccT[2];
#pragma unroll
    for (int d = 0; d < 2; d++)
#pragma unroll
        for (int r = 0; r < 16; r++) oaccT[d][r] = 0.f;
    float m_i = NEG_BIG, l_i = 0.f;

    v8bf kreg[4], vreg[4];
    {   // stage tile k0
        const bf16* ks = &Kb[(size_t)(k0 * 128 + krow) * 256 + kvh * DH + kcb];
        const bf16* vs = &Vtg[(size_t)(kvh * DH + vr) * L_SEQ + k0 * 128 + vcb];
#pragma unroll
        for (int u = 0; u < 4; u++) { kreg[u] = *(const v8bf*)&ks[8 * u]; vreg[u] = *(const v8bf*)&vs[8 * u]; }
#pragma unroll
        for (int u = 0; u < 4; u++) { *(v8bf*)&Ks[krow][kcb + 8 * u] = kreg[u]; *(v8bf*)&Vt[vr][vcb + 8 * u] = vreg[u]; }
    }

    for (int kb = k0; kb < k1; kb++) {
        __syncthreads();
        if (kb + 1 < k1) {
            const bf16* ks = &Kb[(size_t)((kb + 1) * 128 + krow) * 256 + kvh * DH + kcb];
            const bf16* vs = &Vtg[(size_t)(kvh * DH + vr) * L_SEQ + (kb + 1) * 128 + vcb];
#pragma unroll
            for (int u = 0; u < 4; u++) { kreg[u] = *(const v8bf*)&ks[8 * u]; vreg[u] = *(const v8bf*)&vs[8 * u]; }
        }

        // ---- QK^T (swapped): s[n] = S^T[key=n*32+...][q=lane&31] ----
        f32x16 s[4];
        __builtin_amdgcn_s_setprio(1);
#pragma unroll
        for (int n = 0; n < 4; n++) {
#pragma unroll
            for (int r = 0; r < 16; r++) s[n][r] = 0.f;
#pragma unroll
            for (int d16 = 0; d16 < 4; d16++) {
                v8bf av = *(v8bf*)&Ks[n * 32 + l32][d16 * 16 + hi * 8];
                s[n] = __builtin_amdgcn_mfma_f32_32x32x16_bf16(av, qf[d16], s[n], 0, 0, 0);
            }
        }
        __builtin_amdgcn_s_setprio(0);

        // ---- causal mask on diag tile only (scale folded into Q) ----
        if (kb == qb) {
#pragma unroll
            for (int n = 0; n < 4; n++) {
                int kbase = kb * 128 + n * 32 + 4 * hi;
#pragma unroll
                for (int r = 0; r < 16; r++) {
                    int key = kbase + (r & 3) + 8 * (r >> 2);
                    if (key > qrow) s[n][r] = NEG_BIG;
                }
            }
        }

        // ---- online softmax: per-lane max3 reduce + one cross-half shuffle ----
        float mx = NEG_BIG;
#pragma unroll
        for (int n = 0; n < 4; n++)
#pragma unroll
            for (int r = 0; r < 16; r += 2)
                mx = fmaxf(fmaxf(mx, s[n][r]), s[n][r + 1]);
        mx = fmaxf(mx, __shfl_xor(mx, 32));

        // defer-max: only rescale when the tile max materially grew
        if (!__all(mx <= m_i + DEFER_THR)) {
            float mnew = fmaxf(m_i, mx);
            float alpha = exp2f(m_i - mnew);
            l_i *= alpha;
#pragma unroll
            for (int d = 0; d < 2; d++)
#pragma unroll
                for (int r = 0; r < 16; r++) oaccT[d][r] *= alpha;
            m_i = mnew;
        }

        float rs = 0.f;
#pragma unroll
        for (int n = 0; n < 4; n++)
#pragma unroll
            for (int r = 0; r < 16; r++) {
                float pv = exp2f(s[n][r] - m_i);
                s[n][r] = pv;
                rs += pv;
            }
        rs += __shfl_xor(rs, 32);
        l_i += rs;

        // ---- P pack + swap -> PV (no LDS round-trip) ----
        __builtin_amdgcn_s_setprio(1);
#pragma unroll
        for (int n = 0; n < 4; n++) {
#pragma unroll
            for (int u = 0; u < 2; u++) {
                const int ro = u * 8;
                unsigned a0 = pkbf(s[n][ro + 0], s[n][ro + 1]);
                unsigned a1 = pkbf(s[n][ro + 2], s[n][ro + 3]);
                unsigned b0 = pkbf(s[n][ro + 4], s[n][ro + 5]);
                unsigned b1 = pkbf(s[n][ro + 6], s[n][ro + 7]);
#if __has_builtin(__builtin_amdgcn_permlane32_swap)
                auto s0 = __builtin_amdgcn_permlane32_swap(a0, b0, false, false);
                auto s1 = __builtin_amdgcn_permlane32_swap(a1, b1, false, false);
                unsigned w0 = s0[0], w2 = s0[1], w1 = s1[0], w3 = s1[1];
#else
                unsigned t0 = hi ? a0 : b0;
                unsigned r0 = __shfl_xor(t0, 32);
                unsigned w0 = hi ? r0 : a0, w2 = hi ? b0 : r0;
                unsigned t1 = hi ? a1 : b1;
                unsigned r1 = __shfl_xor(t1, 32);
                unsigned w1 = hi ? r1 : a1, w3 = hi ? b1 : r1;
#endif
                union { unsigned uu[4]; v8bf v; } pf;
                pf.uu[0] = w0; pf.uu[1] = w1; pf.uu[2] = w2; pf.uu[3] = w3;
                const int t = n * 2 + u;
#pragma unroll
                for (int dblk = 0; dblk < 2; dblk++) {
                    v8bf av = *(v8bf*)&Vt[dblk * 32 + l32][t * 16 + hi * 8];
                    oaccT[dblk] = __builtin_amdgcn_mfma_f32_32x32x16_bf16(av, pf.v, oaccT[dblk], 0, 0, 0);
                }
            }
        }
        __builtin_amdgcn_s_setprio(0);

        __syncthreads();
        if (kb + 1 < k1) {
#pragma unroll
            for (int u = 0; u < 4; u++) { *(v8bf*)&Ks[krow][kcb + 8 * u] = kreg[u]; *(v8bf*)&Vt[vr][vcb + 8 * u] = vreg[u]; }
        }
    }

    // ---- epilogue: transpose O^T through Ks, coalesced partial write ----
    __syncthreads();
#pragma unroll
    for (int dblk = 0; dblk < 2; dblk++)
#pragma unroll
        for (int r = 0; r < 16; r++) {
            int d = dblk * 32 + (r & 3) + 8 * (r >> 2) + 4 * hi;
            Ks[w * 32 + l32][d] = (bf16)oaccT[dblk][r];
        }
    asm volatile("s_waitcnt lgkmcnt(0)" ::: "memory");
    __builtin_amdgcn_sched_barrier(0);
#pragma unroll
    for (int ii = 0; ii < 4; ii++) {
        int cc = (lane & 1) * 32 + ii * 8;
        int rr = w * 32 + (lane >> 1);
        v8bf ov = *(v8bf*)&Ks[rr][cc];
        *(v8bf*)&Op[(size_t)(qb * 128 + rr) * DMODEL + h * DH + cc] = ov;
    }
    if (hi == 0) {
        mlp[qrow * 2 + 0] = m_i;
        mlp[qrow * 2 + 1] = l_i;
    }
}

// ---------------------------------------------------------------------------
// Combine the two split-K partials into normalized Attn (bf16).
// m values are in log2 domain -> exp2f here.
// ---------------------------------------------------------------------------
__global__ void combine(const bf16* __restrict__ O0, const bf16* __restrict__ O1,
                        const float* __restrict__ ML, bf16* __restrict__ Attn) {
    int gid = blockIdx.x * 256 + threadIdx.x;
    int row = gid >> 8;
    int cg = (gid & 255) * 4;
    int h = cg >> 6;
    const float* ml0 = ML + ((size_t)h * L_SEQ + row) * 2;
    const float* ml1 = ML + ((size_t)(NHEADS + h) * L_SEQ + row) * 2;
    float m0 = ml0[0], l0 = ml0[1], m1 = ml1[0], l1 = ml1[1];
    float m = fmaxf(m0, m1);
    float a0 = exp2f(m0 - m), a1 = exp2f(m1 - m);
    float inv = 1.f / (a0 * l0 + a1 * l1);
    v4bf o0 = *(const v4bf*)&O0[(size_t)row * DMODEL + cg];
    v4bf o1 = *(const v4bf*)&O1[(size_t)row * DMODEL + cg];
    v4bf res;
#pragma unroll
    for (int j = 0; j < 4; j++)
        res[j] = (bf16)((a0 * (float)o0[j] + a1 * (float)o1[j]) * inv);
    *(v4bf*)&Attn[(size_t)row * DMODEL + cg] = res;
}

// ---------------------------------------------------------------------------
extern "C" void kernel_launch(void* const* d_in, const int* in_sizes, int n_in,
                              void* d_out, int out_size, void* d_ws, size_t ws_size,
                              hipStream_t stream) {
    const float* x  = (const float*)d_in[0];
    const float* Wq = (const float*)d_in[1];
    const float* Wk = (const float*)d_in[2];
    const float* Wv = (const float*)d_in[3];
    const float* Wo = (const float*)d_in[4];
    const int*   tp = (const int*)d_in[5];
    float* out = (float*)d_out;

    bf16*  xb    = (bf16*)d_ws;               // 4,194,304 (reused as Attn)
    bf16*  wqkvb = xb    + 4194304;           // 1,572,864
    bf16*  wob   = wqkvb + 1572864;           // 1,048,576
    bf16*  Qb    = wob   + 1048576;           // 4,194,304
    bf16*  Kb    = Qb    + 4194304;           // 1,048,576  [4096][256]
    bf16*  Vtg   = Kb    + 1048576;           // 1,048,576  [256][4096]
    float* MLf   = (float*)(Vtg + 1048576);   // 262,144 f32
    bf16*  Attn  = xb;
    bf16*  O0    = (bf16*)d_out;              // partial z=0 (bf16, 8.4 MB)
    bf16*  O1    = O0 + 4194304;              // partial z=1

    convert_all<<<6656, 256, 0, stream>>>(x, Wq, Wk, Wv, Wo, xb, wqkvb, wob);
    gemm_qkv<<<dim3(32, 12), 512, 0, stream>>>(xb, wqkvb, Qb, Kb, Vtg, tp);
    flash16<<<dim3(NHEADS, 64), 256, 0, stream>>>(Qb, Kb, Vtg, O0, O1, MLf);
    combine<<<4096, 256, 0, stream>>>(O0, O1, MLf, Attn);
    gemm_out<<<dim3(32, 8), 512, 0, stream>>>(Attn, wob, out);
}